// Round 5
// baseline (867.532 us; speedup 1.0000x reference)
//
#include <hip/hip_runtime.h>
#include <type_traits>

typedef _Float16 f16;
typedef _Float16 f16x2 __attribute__((ext_vector_type(2)));
typedef _Float16 f16x4 __attribute__((ext_vector_type(4)));
typedef _Float16 f16x8 __attribute__((ext_vector_type(8)));
typedef float f32x4 __attribute__((ext_vector_type(4)));

__device__ __forceinline__ f32x4 mfma16(f16x8 a, f16x8 b, f32x4 c) {
  return __builtin_amdgcn_mfma_f32_16x16x32_f16(a, b, c, 0, 0, 0);
}

__device__ __forceinline__ float sigmoid_(float x) { return 1.f / (1.f + __expf(-x)); }
__device__ __forceinline__ float tanh_(float x) { return 1.f - 2.f / (__expf(2.f * x) + 1.f); }

// ---------------------------------------------------------------------------
// fp32 -> fp16 conversion, 4 elements/thread
// ---------------------------------------------------------------------------
__global__ void cvt_kernel(const float* __restrict__ src, f16* __restrict__ dst, int n4) {
  int i = blockIdx.x * 256 + threadIdx.x;
  if (i < n4) {
    float4 v = ((const float4*)src)[i];
    f16x4 h = {(f16)v.x, (f16)v.y, (f16)v.z, (f16)v.w};
    ((f16x4*)dst)[i] = h;
  }
}

// fused conversion of W_vt, W_ih, W_hh (exactly n0+n1+n2 threads-of-4)
__global__ void cvt3_kernel(const float* __restrict__ s0, f16* __restrict__ d0, int n0,
                            const float* __restrict__ s1, f16* __restrict__ d1, int n1,
                            const float* __restrict__ s2, f16* __restrict__ d2, int n2) {
  int i = blockIdx.x * 256 + threadIdx.x;
  const float* s;
  f16* d;
  int j;
  if (i < n0) {
    s = s0; d = d0; j = i;
  } else if (i < n0 + n1) {
    s = s1; d = d1; j = i - n0;
  } else if (i < n0 + n1 + n2) {
    s = s2; d = d2; j = i - n0 - n1;
  } else {
    return;
  }
  float4 v = ((const float4*)s)[j];
  f16x4 h = {(f16)v.x, (f16)v.y, (f16)v.z, (f16)v.w};
  ((f16x4*)d)[j] = h;
}

// ---------------------------------------------------------------------------
// GEMM1: P[split][2048][512] f16 partials = v[2048,20000] @ W_down^T slabs.
// 128x256 tiles (A re-staged x2, B x16 -> ~656 MB L2 traffic, half of R4's
// 1.3 GB). 512 blocks = 2/CU, 8 waves/CU. BT = f16 (pre-converted, big-ws
// path) or float (fallback). XCD = blockIdx.x%8 pins each B k-slab to one
// XCD's L2; A-sharing pair (n0=0,1) = adjacent blockIdx.y -> same XCD.
// ---------------------------------------------------------------------------
template <typename BT>
__global__ __launch_bounds__(256, 2) void gemm1_kernel(
    const float* __restrict__ A, const BT* __restrict__ B, f16* __restrict__ P) {
  constexpr bool BF32 = std::is_same<BT, float>::value;
  constexpr int K = 20000;
  __shared__ f16 Al[128][40];
  __shared__ f16 Bl[256][40];
  const int tid = threadIdx.x;
  const int split = blockIdx.x;  // 0..15
  const int m0 = (int)(blockIdx.y >> 1) * 128, n0 = (int)(blockIdx.y & 1) * 256;
  const int it0 = (split * 625) >> 4, it1 = ((split + 1) * 625) >> 4;
  const int wid = tid >> 6, lane = tid & 63;
  const int wm = wid & 1, wn = wid >> 1;  // wave tile 64m x 128n
  const int lm = lane & 15, quad = lane >> 4;
  const int arow = tid >> 1, aseg = (tid & 1) * 16;

  const float* aptr = A + (size_t)(m0 + arow) * K + aseg;
  const BT* bptr = B + (size_t)(n0 + tid) * K;

  using BReg = typename std::conditional<BF32, float4, f16x8>::type;
  constexpr int NB = BF32 ? 8 : 4;
  float4 Ar[4];
  BReg Br[NB];
  {
    int k0 = it0 * 32;
#pragma unroll
    for (int j = 0; j < 4; ++j) Ar[j] = *(const float4*)(aptr + k0 + j * 4);
#pragma unroll
    for (int j = 0; j < NB; ++j) Br[j] = ((const BReg*)(bptr + k0))[j];
  }

  f32x4 acc[4][8];
#pragma unroll
  for (int i = 0; i < 4; ++i)
#pragma unroll
    for (int j = 0; j < 8; ++j) acc[i][j] = (f32x4){0.f, 0.f, 0.f, 0.f};

  for (int it = it0; it < it1; ++it) {
    __syncthreads();
    {
      f16x8 pa0 = {(f16)Ar[0].x, (f16)Ar[0].y, (f16)Ar[0].z, (f16)Ar[0].w,
                   (f16)Ar[1].x, (f16)Ar[1].y, (f16)Ar[1].z, (f16)Ar[1].w};
      f16x8 pa1 = {(f16)Ar[2].x, (f16)Ar[2].y, (f16)Ar[2].z, (f16)Ar[2].w,
                   (f16)Ar[3].x, (f16)Ar[3].y, (f16)Ar[3].z, (f16)Ar[3].w};
      *(f16x8*)&Al[arow][aseg] = pa0;
      *(f16x8*)&Al[arow][aseg + 8] = pa1;
      if constexpr (BF32) {
#pragma unroll
        for (int j = 0; j < 4; ++j) {
          float4 lo = Br[2 * j], hi = Br[2 * j + 1];
          f16x8 pb = {(f16)lo.x, (f16)lo.y, (f16)lo.z, (f16)lo.w,
                      (f16)hi.x, (f16)hi.y, (f16)hi.z, (f16)hi.w};
          *(f16x8*)&Bl[tid][j * 8] = pb;
        }
      } else {
#pragma unroll
        for (int j = 0; j < 4; ++j) *(f16x8*)&Bl[tid][j * 8] = Br[j];
      }
    }
    if (it + 1 < it1) {
      int kn = (it + 1) * 32;
#pragma unroll
      for (int j = 0; j < 4; ++j) Ar[j] = *(const float4*)(aptr + kn + j * 4);
#pragma unroll
      for (int j = 0; j < NB; ++j) Br[j] = ((const BReg*)(bptr + kn))[j];
    }
    __syncthreads();
    f16x8 af[4];
#pragma unroll
    for (int mi = 0; mi < 4; ++mi) af[mi] = *(const f16x8*)&Al[wm * 64 + mi * 16 + lm][quad * 8];
#pragma unroll
    for (int ni = 0; ni < 8; ++ni) {
      f16x8 bf = *(const f16x8*)&Bl[wn * 128 + ni * 16 + lm][quad * 8];
#pragma unroll
      for (int mi = 0; mi < 4; ++mi) acc[mi][ni] = mfma16(af[mi], bf, acc[mi][ni]);
    }
  }
  size_t base = (size_t)split * 2048;
#pragma unroll
  for (int mi = 0; mi < 4; ++mi)
#pragma unroll
    for (int ni = 0; ni < 8; ++ni)
#pragma unroll
      for (int r = 0; r < 4; ++r) {
        int row = m0 + wm * 64 + mi * 16 + quad * 4 + r;
        int col = n0 + wn * 128 + ni * 16 + lm;
        P[(base + row) * 512 + col] = (f16)acc[mi][ni][r];
      }
}

// ---------------------------------------------------------------------------
// build vt[2048,640] f16 = [ sum_16 P | t*Wt_up_w + Wt_up_b ]
// ---------------------------------------------------------------------------
__global__ void build_vt_kernel(const f16* __restrict__ P, const float* __restrict__ t,
                                const float* __restrict__ wtw, const float* __restrict__ wtb,
                                f16* __restrict__ vt) {
  int m = blockIdx.x;
  float tv = t[m];
  for (int c = threadIdx.x; c < 640; c += 256) {
    float val;
    if (c < 512) {
      val = 0.f;
#pragma unroll
      for (int s = 0; s < 16; ++s) val += (float)P[((size_t)s * 2048 + m) * 512 + c];
    } else {
      val = tv * wtw[c - 512] + wtb[c - 512];
    }
    vt[(size_t)m * 640 + c] = (f16)val;
  }
}

// ---------------------------------------------------------------------------
// Tiled fp16 GEMM: C[M,N] = A[M,K] @ Bt[N,K]^T. EPI 0: plain f16 store.
// EPI 1: xg persistent-LSTM layout [s=l][bid][tid][g*2+h_lo] + bias add, where
// bid=(h>>4)*4+(b>>5), tid=((h&15)>>1)*32+(b&31)  (l=row&15, b=row>>4,
// g=col>>10, h=col&1023).
// ---------------------------------------------------------------------------
template <int TM, int TN, int EPI>
__global__ __launch_bounds__(256, 4) void gemmT_kernel(
    const f16* __restrict__ A, const f16* __restrict__ B, f16* __restrict__ out,
    const float* __restrict__ bias0, const float* __restrict__ bias1, int K_iters, int K,
    int N) {
  constexpr int FM = TM / 32, FN = TN / 32;
  __shared__ f16 Al[TM][40];
  __shared__ f16 Bl[TN][40];
  int tid = threadIdx.x;
  int m0 = blockIdx.y * TM, n0 = blockIdx.x * TN;
  int wid = tid >> 6, lane = tid & 63;
  int wm = wid & 1, wn = wid >> 1;
  int lm = lane & 15, quad = lane >> 4;

  f32x4 acc[FM][FN];
#pragma unroll
  for (int i = 0; i < FM; ++i)
#pragma unroll
    for (int j = 0; j < FN; ++j) acc[i][j] = (f32x4){0.f, 0.f, 0.f, 0.f};

  for (int it = 0; it < K_iters; ++it) {
    int k0 = it * 32;
    __syncthreads();
#pragma unroll
    for (int r = 0; r < TM / 64; ++r) {
      int slot = r * 256 + tid;
      int row = slot >> 2, seg = slot & 3;
      *(f16x8*)&Al[row][seg * 8] = *(const f16x8*)(A + (size_t)(m0 + row) * K + k0 + seg * 8);
    }
#pragma unroll
    for (int r = 0; r < TN / 64; ++r) {
      int slot = r * 256 + tid;
      int row = slot >> 2, seg = slot & 3;
      *(f16x8*)&Bl[row][seg * 8] = *(const f16x8*)(B + (size_t)(n0 + row) * K + k0 + seg * 8);
    }
    __syncthreads();
    f16x8 af[FM];
#pragma unroll
    for (int mi = 0; mi < FM; ++mi)
      af[mi] = *(const f16x8*)&Al[wm * (TM / 2) + mi * 16 + lm][quad * 8];
#pragma unroll
    for (int ni = 0; ni < FN; ++ni) {
      f16x8 bf = *(const f16x8*)&Bl[wn * (TN / 2) + ni * 16 + lm][quad * 8];
#pragma unroll
      for (int mi = 0; mi < FM; ++mi) acc[mi][ni] = mfma16(af[mi], bf, acc[mi][ni]);
    }
  }
#pragma unroll
  for (int mi = 0; mi < FM; ++mi)
#pragma unroll
    for (int ni = 0; ni < FN; ++ni)
#pragma unroll
      for (int r = 0; r < 4; ++r) {
        int row = m0 + wm * (TM / 2) + mi * 16 + quad * 4 + r;
        int col = n0 + wn * (TN / 2) + ni * 16 + lm;
        float val = acc[mi][ni][r];
        if (EPI == 0) {
          out[(size_t)row * N + col] = (f16)val;
        } else {
          int l = row & 15, b = row >> 4;
          int g = col >> 10, h = col & 1023;
          int bid = (h >> 4) * 4 + (b >> 5);
          int t2 = ((h & 15) >> 1) * 32 + (b & 31);
          size_t off = ((((size_t)l * 256 + bid) * 256 + t2) << 3) + g * 2 + (h & 1);
          out[off] = (f16)(val + bias0[col] + bias1[col]);
        }
      }
}

// ---------------------------------------------------------------------------
// Persistent LSTM, all 16 steps. 256 blocks x 256 thr (1/CU, all CUs).
// Per block: W_hh slice (4 gates x 16 hid, K=1024) in LDS for the whole
// kernel; xg slice loaded per step as ONE coalesced f16x8/thread; c in regs;
// h (64 KB/block) fully prefetched into VGPRs each step (batched latency);
// grid barrier (per-step counter + agent fences) between steps. Only h
// crosses the coherence boundary.
// ---------------------------------------------------------------------------
__global__ __launch_bounds__(256, 1) void lstm_persist_kernel(
    const f16* __restrict__ Whh, const f16* __restrict__ xg, f16* __restrict__ B0,
    f16* __restrict__ B1, unsigned* __restrict__ bar) {
  __shared__ f16 Wl[64 * 1032];    // stride 1032 f16: +4 dw mod 32 -> conflict-free b128
  __shared__ float gl[4][32][17];  // gate exchange
  const int tid = threadIdx.x;
  const int w = tid >> 6, lane = tid & 63;
  const int lm = lane & 15, quad = lane >> 4;
  const int bid = blockIdx.x;
  const int h0 = (bid >> 2) * 16, b0 = (bid & 3) * 32;

  // one-time W_hh slice: row r -> gate r>>4, hid h0+(r&15)
  for (int i = tid; i < 8192; i += 256) {
    int r = i >> 7, c8 = (i & 127) * 8;
    *(f16x8*)&Wl[r * 1032 + c8] =
        *(const f16x8*)(Whh + ((size_t)((r >> 4) << 10) + h0 + (r & 15)) * 1024 + c8);
  }
  float c0 = 0.f, c1 = 0.f;
  const int bl = tid & 31, h2 = tid >> 5;
  const f16* xbase = xg + ((size_t)bid * 256 + tid) * 8;
  __syncthreads();

  for (int s = 0; s < 16; ++s) {
    f16x8 xv = *(const f16x8*)(xbase + (size_t)s * 524288);
    f32x4 acc0 = {0.f, 0.f, 0.f, 0.f}, acc1 = {0.f, 0.f, 0.f, 0.f};
    if (s > 0) {
      const f16* hcur = (s & 1) ? B0 : B1;  // step s reads what step s-1 wrote
      const f16* hr0 = hcur + (size_t)(b0 + lm) * 1024 + quad * 8;
      const f16* hr1 = hcur + (size_t)(b0 + 16 + lm) * 1024 + quad * 8;
      f16x8 ha0[32], ha1[32];
#pragma unroll
      for (int it = 0; it < 32; ++it) {  // 64 batched loads: MLP covers L3 latency
        ha0[it] = *(const f16x8*)(hr0 + it * 32);
        ha1[it] = *(const f16x8*)(hr1 + it * 32);
      }
      const f16* wb = &Wl[(w * 16 + lm) * 1032 + quad * 8];
#pragma unroll
      for (int it = 0; it < 32; ++it) {
        f16x8 bfr = *(const f16x8*)(wb + it * 32);
        acc0 = mfma16(ha0[it], bfr, acc0);
        acc1 = mfma16(ha1[it], bfr, acc1);
      }
    }
#pragma unroll
    for (int r = 0; r < 4; ++r) {
      gl[w][quad * 4 + r][lm] = acc0[r];
      gl[w][16 + quad * 4 + r][lm] = acc1[r];
    }
    __syncthreads();
    float hh[2];
#pragma unroll
    for (int j = 0; j < 2; ++j) {
      int hl = h2 * 2 + j;
      float gi = (float)xv[j] + gl[0][bl][hl];
      float gf = (float)xv[2 + j] + gl[1][bl][hl];
      float gg = (float)xv[4 + j] + gl[2][bl][hl];
      float go = (float)xv[6 + j] + gl[3][bl][hl];
      float iv = sigmoid_(gi), fv = sigmoid_(gf), gv = tanh_(gg), ov = sigmoid_(go);
      float& cc = j ? c1 : c0;
      cc = fv * cc + iv * gv;
      hh[j] = ov * tanh_(cc);
    }
    f16* hnxt = (s & 1) ? B1 : B0;
    f16x2 hv = {(f16)hh[0], (f16)hh[1]};
    *(f16x2*)(hnxt + (size_t)(b0 + bl) * 1024 + h0 + h2 * 2) = hv;
    if (s < 15) {
      __syncthreads();  // drains vmcnt: h stores in L2
      if (tid == 0) {
        __threadfence();  // release: writeback to coherent point
        __hip_atomic_fetch_add(bar + s * 16, 1u, __ATOMIC_RELAXED, __HIP_MEMORY_SCOPE_AGENT);
        while (__hip_atomic_load(bar + s * 16, __ATOMIC_RELAXED, __HIP_MEMORY_SCOPE_AGENT) <
               256u)
          __builtin_amdgcn_s_sleep(2);
        __threadfence();  // acquire: invalidate L1/L2
      }
      __syncthreads();
    }
  }
}

// ---------------------------------------------------------------------------
// pred[b] = dot(h[b] (f16), lin_w) + lin_b
// ---------------------------------------------------------------------------
__global__ void pred_kernel(const f16* __restrict__ h, const float* __restrict__ w,
                            const float* __restrict__ b, float* __restrict__ out) {
  int bb = blockIdx.x, tid = threadIdx.x;
  f16x4 hv = *(const f16x4*)(h + (size_t)bb * 1024 + tid * 4);
  float4 wv = *(const float4*)(w + tid * 4);
  float s = (float)hv[0] * wv.x + (float)hv[1] * wv.y + (float)hv[2] * wv.z + (float)hv[3] * wv.w;
#pragma unroll
  for (int off = 32; off > 0; off >>= 1) s += __shfl_down(s, off);
  __shared__ float red[4];
  if ((tid & 63) == 0) red[tid >> 6] = s;
  __syncthreads();
  if (tid == 0) out[bb] = red[0] + red[1] + red[2] + red[3] + b[0];
}

// ---------------------------------------------------------------------------
extern "C" void kernel_launch(void* const* d_in, const int* in_sizes, int n_in,
                              void* d_out, int out_size, void* d_ws, size_t ws_size,
                              hipStream_t stream) {
  (void)in_sizes; (void)n_in; (void)out_size;
  const float* v      = (const float*)d_in[0];
  const float* t      = (const float*)d_in[1];
  const float* W_down = (const float*)d_in[2];
  const float* Wt_w   = (const float*)d_in[3];
  const float* Wt_b   = (const float*)d_in[4];
  const float* W_vt   = (const float*)d_in[5];
  const float* W_ih   = (const float*)d_in[6];
  const float* W_hh   = (const float*)d_in[7];
  const float* b_ih   = (const float*)d_in[8];
  const float* b_hh   = (const float*)d_in[9];
  const float* lin_w  = (const float*)d_in[10];
  const float* lin_b  = (const float*)d_in[11];

  char* ws = (char*)d_ws;
  // common: W_vt/W_ih/W_hh f16
  constexpr size_t OFF_WVT = 0;        // 655,360
  constexpr size_t OFF_WIH = 655360;   // 4,194,304
  constexpr size_t OFF_WHH = 4849664;  // 8,388,608 -> end 13,238,272
  // big-ws path A: + W_down f16 (20,480,000)
  constexpr size_t A_WDOWN = 13238272;
  constexpr size_t A_VT  = 33718272;   // 2,621,440
  constexpr size_t A_IN  = 36339712;   // 2,097,152
  constexpr size_t A_P   = 38436864;   // 33,554,432 (xg [16][256][256][8] overlays)
  constexpr size_t A_H0  = 71991296;   // 262,144
  constexpr size_t A_H1  = 72253440;   // 262,144
  constexpr size_t A_BAR = 72515584;   // 1,024 -> need 72,516,608
  // fallback path B (no W_down f16): proven-size footprint
  constexpr size_t B_VT  = 13238272;
  constexpr size_t B_IN  = 15859712;
  constexpr size_t B_P   = 17956864;
  constexpr size_t B_H0  = 51511296;
  constexpr size_t B_H1  = 51773440;
  constexpr size_t B_BAR = 52035584;   // -> need 52,036,608

  const bool big = ws_size >= 72516608ull;  // constant across calls: graph-safe
  f16* wvt16  = (f16*)(ws + OFF_WVT);
  f16* wih16  = (f16*)(ws + OFF_WIH);
  f16* whh16  = (f16*)(ws + OFF_WHH);
  f16* vt16   = (f16*)(ws + (big ? A_VT : B_VT));
  f16* in16   = (f16*)(ws + (big ? A_IN : B_IN));
  f16* pxg    = (f16*)(ws + (big ? A_P : B_P));
  f16* hb0    = (f16*)(ws + (big ? A_H0 : B_H0));
  f16* hb1    = (f16*)(ws + (big ? A_H1 : B_H1));
  unsigned* bar = (unsigned*)(ws + (big ? A_BAR : B_BAR));

  hipMemsetAsync(bar, 0, 1024, stream);

  cvt3_kernel<<<6464, 256, 0, stream>>>(W_vt, wvt16, 81920, W_ih, wih16, 524288, W_hh, whh16,
                                        1048576);
  if (big) {
    f16* wdown16 = (f16*)(ws + A_WDOWN);
    cvt_kernel<<<10000, 256, 0, stream>>>(W_down, wdown16, 2560000);
    gemm1_kernel<f16><<<dim3(16, 32), 256, 0, stream>>>(v, wdown16, pxg);
  } else {
    gemm1_kernel<float><<<dim3(16, 32), 256, 0, stream>>>(v, W_down, pxg);
  }
  build_vt_kernel<<<2048, 256, 0, stream>>>(pxg, t, Wt_w, Wt_b, vt16);
  // inputs[2048,512] = vt @ W_vt^T : K=640
  gemmT_kernel<64, 64, 0><<<dim3(8, 32), 256, 0, stream>>>(vt16, wvt16, in16, nullptr, nullptr,
                                                           20, 640, 512);
  // xg (persistent layout) = inputs @ W_ih^T + b : K=512
  gemmT_kernel<64, 128, 1><<<dim3(32, 32), 256, 0, stream>>>(in16, wih16, pxg, b_ih, b_hh, 16,
                                                             512, 4096);
  lstm_persist_kernel<<<256, 256, 0, stream>>>(whh16, pxg, hb0, hb1, bar);
  pred_kernel<<<128, 256, 0, stream>>>(hb1, lin_w, lin_b, (float*)d_out);
}